// Round 1
// baseline (398.294 us; speedup 1.0000x reference)
//
#include <hip/hip_runtime.h>

#define TPB 256

__global__ __launch_bounds__(TPB, 1)
void mlp_fused(const float* __restrict__ x,
               const float* __restrict__ W1, const float* __restrict__ b1,
               const float* __restrict__ Wmid, const float* __restrict__ bmid,
               const float* __restrict__ W30, const float* __restrict__ b30,
               float* __restrict__ out, int nrows)
{
    const int row = blockIdx.x * TPB + threadIdx.x;
    if (row >= nrows) return;

    const float* xrow = x + (size_t)row * 784;

    // fc1 accumulators
    float h[20];
#pragma unroll
    for (int k = 0; k < 20; ++k) h[k] = b1[k];

    // fc1: 784 cols in 49 chunks of 16 floats (4 x float4), 1-deep prefetch.
    // Weight loads are wave-uniform -> expect s_load_dwordx4 (scalar cache),
    // feeding v_fma_f32 via the SGPR operand slot.
    float4 buf0 = *(const float4*)(xrow +  0);
    float4 buf1 = *(const float4*)(xrow +  4);
    float4 buf2 = *(const float4*)(xrow +  8);
    float4 buf3 = *(const float4*)(xrow + 12);

#pragma unroll 1
    for (int c = 0; c < 49; ++c) {
        float4 n0, n1, n2, n3;
        const bool more = (c < 48);
        if (more) {
            const float* p = xrow + (c + 1) * 16;
            n0 = *(const float4*)(p + 0);
            n1 = *(const float4*)(p + 4);
            n2 = *(const float4*)(p + 8);
            n3 = *(const float4*)(p + 12);
        }
        const int base = c * 16;
        const float4 xv0 = buf0, xv1 = buf1, xv2 = buf2, xv3 = buf3;
#pragma unroll
        for (int k = 0; k < 20; ++k) {
            const float* wk = W1 + k * 784 + base;
            const float4 w0 = *(const float4*)(wk + 0);
            const float4 w1v = *(const float4*)(wk + 4);
            const float4 w2 = *(const float4*)(wk + 8);
            const float4 w3 = *(const float4*)(wk + 12);
            float a = h[k];
            a = fmaf(xv0.x, w0.x, a);  a = fmaf(xv0.y, w0.y, a);
            a = fmaf(xv0.z, w0.z, a);  a = fmaf(xv0.w, w0.w, a);
            a = fmaf(xv1.x, w1v.x, a); a = fmaf(xv1.y, w1v.y, a);
            a = fmaf(xv1.z, w1v.z, a); a = fmaf(xv1.w, w1v.w, a);
            a = fmaf(xv2.x, w2.x, a);  a = fmaf(xv2.y, w2.y, a);
            a = fmaf(xv2.z, w2.z, a);  a = fmaf(xv2.w, w2.w, a);
            a = fmaf(xv3.x, w3.x, a);  a = fmaf(xv3.y, w3.y, a);
            a = fmaf(xv3.z, w3.z, a);  a = fmaf(xv3.w, w3.w, a);
            h[k] = a;
        }
        if (more) { buf0 = n0; buf1 = n1; buf2 = n2; buf3 = n3; }
    }
#pragma unroll
    for (int k = 0; k < 20; ++k) h[k] = fmaxf(h[k], 0.0f);

    // fc2..fc29: 28 layers of 20x20 + ReLU. Weights/biases wave-uniform.
#pragma unroll 1
    for (int l = 0; l < 28; ++l) {
        const float* wl = Wmid + l * 400;
        const float* bl = bmid + l * 20;
        float g[20];
#pragma unroll
        for (int o = 0; o < 20; ++o) {
            float acc = bl[o];
            const float* wo = wl + o * 20;
#pragma unroll
            for (int i = 0; i < 20; i += 4) {
                const float4 w = *(const float4*)(wo + i);
                acc = fmaf(h[i + 0], w.x, acc);
                acc = fmaf(h[i + 1], w.y, acc);
                acc = fmaf(h[i + 2], w.z, acc);
                acc = fmaf(h[i + 3], w.w, acc);
            }
            g[o] = fmaxf(acc, 0.0f);
        }
#pragma unroll
        for (int o = 0; o < 20; ++o) h[o] = g[o];
    }

    // fc30: 20 -> 10, no ReLU
    float o10[10];
#pragma unroll
    for (int o = 0; o < 10; ++o) {
        float acc = b30[o];
        const float* wo = W30 + o * 20;
#pragma unroll
        for (int i = 0; i < 20; i += 4) {
            const float4 w = *(const float4*)(wo + i);
            acc = fmaf(h[i + 0], w.x, acc);
            acc = fmaf(h[i + 1], w.y, acc);
            acc = fmaf(h[i + 2], w.z, acc);
            acc = fmaf(h[i + 3], w.w, acc);
        }
        o10[o] = acc;
    }

    // store 10 floats as 5x float2 (row*40 B is 8-byte aligned)
    float2* orow = (float2*)(out + (size_t)row * 10);
    orow[0] = make_float2(o10[0], o10[1]);
    orow[1] = make_float2(o10[2], o10[3]);
    orow[2] = make_float2(o10[4], o10[5]);
    orow[3] = make_float2(o10[6], o10[7]);
    orow[4] = make_float2(o10[8], o10[9]);
}

extern "C" void kernel_launch(void* const* d_in, const int* in_sizes, int n_in,
                              void* d_out, int out_size, void* d_ws, size_t ws_size,
                              hipStream_t stream)
{
    const float* x    = (const float*)d_in[0];
    const float* W1   = (const float*)d_in[1];
    const float* b1   = (const float*)d_in[2];
    const float* Wmid = (const float*)d_in[3];
    const float* bmid = (const float*)d_in[4];
    const float* W30  = (const float*)d_in[5];
    const float* b30  = (const float*)d_in[6];
    float* out = (float*)d_out;

    const int nrows = in_sizes[0] / 784;
    const int grid = (nrows + TPB - 1) / TPB;
    mlp_fused<<<grid, TPB, 0, stream>>>(x, W1, b1, Wmid, bmid, W30, b30, out, nrows);
}

// Round 2
// 123.007 us; speedup vs baseline: 3.2380x; 3.2380x over previous
//
#include <hip/hip_runtime.h>

#define TPB 256

__device__ __forceinline__ float4 ldf4(const float* p) { return *(const float4*)p; }

// Block = 4 waves x 64 lanes. Tile = 64 rows (lane = row).
// Phase 1: wave w computes partial fc1 dot over cols [196w,196w+196) -> LDS reduce.
// Phase 2: wave w computes mid-layer outputs [5w,5w+5) for all 64 rows; h ping-pongs in LDS.
// Weights are wave-uniform (scalar loads); x / LDS are the only per-lane streams.
__global__ __launch_bounds__(TPB, 4)
void mlp_fused2(const float* __restrict__ x,
                const float* __restrict__ W1, const float* __restrict__ b1,
                const float* __restrict__ Wmid, const float* __restrict__ bmid,
                const float* __restrict__ W30, const float* __restrict__ b30,
                float* __restrict__ out, int nrows)
{
    __shared__ float hp[4 * 20 * 64];    // fc1 partials [wave][i][lane]
    __shared__ float hbuf[2 * 20 * 64];  // ping-pong activations [buf][i][lane]

    const int lane = threadIdx.x & 63;
    const int wv   = __builtin_amdgcn_readfirstlane(threadIdx.x >> 6); // force SGPR
    const int row  = blockIdx.x * 64 + lane;
    const int rowc = row < nrows ? row : nrows - 1;

    // ---------------- Phase 1: fc1 partial (196 cols per wave) ----------------
    const float* xp    = x  + (size_t)rowc * 784 + wv * 196;
    const float* wbase = W1 + wv * 196;

    float p[20];
#pragma unroll
    for (int i = 0; i < 20; ++i) p[i] = 0.0f;

    // 196 = 12*16 + 4. 1-deep prefetch of 16 floats.
    float4 a0 = ldf4(xp + 0), a1 = ldf4(xp + 4), a2 = ldf4(xp + 8), a3 = ldf4(xp + 12);

#pragma unroll 1
    for (int c = 0; c < 12; ++c) {
        float4 n0, n1, n2, n3;
        if (c < 11) {
            const float* q = xp + (c + 1) * 16;
            n0 = ldf4(q); n1 = ldf4(q + 4); n2 = ldf4(q + 8); n3 = ldf4(q + 12);
        } else {
            n0 = ldf4(xp + 192);  // tail prefetch (4 floats)
        }
        const int base = c * 16;
        const float4 x0 = a0, x1 = a1, x2 = a2, x3 = a3;
#pragma unroll
        for (int k = 0; k < 20; ++k) {
            const float* wk = wbase + k * 784 + base;   // wave-uniform -> s_load
            const float4 w0 = ldf4(wk + 0);
            const float4 w1 = ldf4(wk + 4);
            const float4 w2 = ldf4(wk + 8);
            const float4 w3 = ldf4(wk + 12);
            float acc = p[k];
            acc = fmaf(x0.x, w0.x, acc); acc = fmaf(x0.y, w0.y, acc);
            acc = fmaf(x0.z, w0.z, acc); acc = fmaf(x0.w, w0.w, acc);
            acc = fmaf(x1.x, w1.x, acc); acc = fmaf(x1.y, w1.y, acc);
            acc = fmaf(x1.z, w1.z, acc); acc = fmaf(x1.w, w1.w, acc);
            acc = fmaf(x2.x, w2.x, acc); acc = fmaf(x2.y, w2.y, acc);
            acc = fmaf(x2.z, w2.z, acc); acc = fmaf(x2.w, w2.w, acc);
            acc = fmaf(x3.x, w3.x, acc); acc = fmaf(x3.y, w3.y, acc);
            acc = fmaf(x3.z, w3.z, acc); acc = fmaf(x3.w, w3.w, acc);
            p[k] = acc;
        }
        a0 = n0; a1 = n1; a2 = n2; a3 = n3;
    }
    // tail: 4 floats (in a0)
#pragma unroll
    for (int k = 0; k < 20; ++k) {
        const float4 w0 = ldf4(wbase + k * 784 + 192);
        p[k] = fmaf(a0.x, w0.x, fmaf(a0.y, w0.y, fmaf(a0.z, w0.z, fmaf(a0.w, w0.w, p[k]))));
    }

#pragma unroll
    for (int i = 0; i < 20; ++i) hp[(wv * 20 + i) * 64 + lane] = p[i];
    __syncthreads();

    // ---------------- Reduce + bias + ReLU (each wave keeps full h in regs) ----
    float h[20];
#pragma unroll
    for (int i = 0; i < 20; ++i) {
        const float s = b1[i] + ((hp[(0 * 20 + i) * 64 + lane] + hp[(1 * 20 + i) * 64 + lane]) +
                                 (hp[(2 * 20 + i) * 64 + lane] + hp[(3 * 20 + i) * 64 + lane]));
        h[i] = fmaxf(s, 0.0f);
    }

    // ---------------- Phase 2: 28 mid layers, split 5 outputs per wave ---------
    int cur = 0;
#pragma unroll 1
    for (int l = 0; l < 28; ++l) {
        const float* wl = Wmid + l * 400 + wv * 100;  // wave-uniform
        const float* bl = bmid + l * 20 + wv * 5;
        float g[5];
#pragma unroll
        for (int o = 0; o < 5; ++o) {
            float acc = bl[o];
            const float* wo = wl + o * 20;
#pragma unroll
            for (int i = 0; i < 20; i += 4) {
                const float4 w = ldf4(wo + i);
                acc = fmaf(h[i + 0], w.x, acc);
                acc = fmaf(h[i + 1], w.y, acc);
                acc = fmaf(h[i + 2], w.z, acc);
                acc = fmaf(h[i + 3], w.w, acc);
            }
            g[o] = fmaxf(acc, 0.0f);
        }
#pragma unroll
        for (int o = 0; o < 5; ++o) hbuf[cur * 1280 + (wv * 5 + o) * 64 + lane] = g[o];
        __syncthreads();
#pragma unroll
        for (int i = 0; i < 20; ++i) h[i] = hbuf[cur * 1280 + i * 64 + lane];
        cur ^= 1;
    }

    // ---------------- fc30: waves 0,1 produce outputs 0..9 --------------------
    if (wv < 2) {
        float o5[5];
#pragma unroll
        for (int oo = 0; oo < 5; ++oo) {
            const int o = wv * 5 + oo;
            float acc = b30[o];
            const float* wo = W30 + o * 20;
#pragma unroll
            for (int i = 0; i < 20; i += 4) {
                const float4 w = ldf4(wo + i);
                acc = fmaf(h[i + 0], w.x, acc);
                acc = fmaf(h[i + 1], w.y, acc);
                acc = fmaf(h[i + 2], w.z, acc);
                acc = fmaf(h[i + 3], w.w, acc);
            }
            o5[oo] = acc;
        }
        if (row < nrows) {
#pragma unroll
            for (int oo = 0; oo < 5; ++oo) out[(size_t)row * 10 + wv * 5 + oo] = o5[oo];
        }
    }
}

extern "C" void kernel_launch(void* const* d_in, const int* in_sizes, int n_in,
                              void* d_out, int out_size, void* d_ws, size_t ws_size,
                              hipStream_t stream)
{
    const float* x    = (const float*)d_in[0];
    const float* W1   = (const float*)d_in[1];
    const float* b1   = (const float*)d_in[2];
    const float* Wmid = (const float*)d_in[3];
    const float* bmid = (const float*)d_in[4];
    const float* W30  = (const float*)d_in[5];
    const float* b30  = (const float*)d_in[6];
    float* out = (float*)d_out;

    const int nrows = in_sizes[0] / 784;
    const int grid = (nrows + 63) / 64;   // 64 rows per block
    mlp_fused2<<<grid, TPB, 0, stream>>>(x, W1, b1, Wmid, bmid, W30, b30, out, nrows);
}

// Round 4
// 61.736 us; speedup vs baseline: 6.4515x; 1.9925x over previous
//
#include <hip/hip_runtime.h>

typedef __attribute__((ext_vector_type(8))) short short8;
typedef __attribute__((ext_vector_type(16))) float f32x16;

#define MFMA(A, B, C) __builtin_amdgcn_mfma_f32_32x32x16_bf16(A, B, C, 0, 0, 0)

__device__ __forceinline__ float4 ldf4(const float* p) { return *(const float4*)p; }

__device__ __forceinline__ short8 mk8(unsigned w0, unsigned w1, unsigned w2, unsigned w3) {
    union { unsigned u[4]; short8 s; } t;
    t.u[0] = w0; t.u[1] = w1; t.u[2] = w2; t.u[3] = w3;
    return t.s;
}

// pack bf16-truncations of (a,b): low16 = top16(a), high16 = top16(b)
__device__ __forceinline__ unsigned packhi2(float a, float b) {
    return __builtin_amdgcn_perm(__float_as_uint(b), __float_as_uint(a), 0x07060302u);
}
__device__ __forceinline__ float lopart(float v) {
    return v - __uint_as_float(__float_as_uint(v) & 0xFFFF0000u);
}

struct Frag { short8 h, l; };

// 8 consecutive f32 -> hi/lo bf16x8 fragments (elem j = value j)
__device__ __forceinline__ Frag cvt8(float4 a, float4 b) {
    Frag f;
    f.h = mk8(packhi2(a.x, a.y), packhi2(a.z, a.w),
              packhi2(b.x, b.y), packhi2(b.z, b.w));
    f.l = mk8(packhi2(lopart(a.x), lopart(a.y)), packhi2(lopart(a.z), lopart(a.w)),
              packhi2(lopart(b.x), lopart(b.y)), packhi2(lopart(b.z), lopart(b.w)));
    return f;
}

// v_permlane32_swap_b32 vdst, vsrc : vdst' = [vdst_lo, vsrc_lo], vsrc' = [vdst_hi, vsrc_hi]
// (VDST lanes 32-63 exchange with SRC lanes 0-31 — CDNA4 ISA)
__device__ __forceinline__ void plswap(unsigned& lo, unsigned& hi) {
    asm("v_permlane32_swap_b32 %0, %1" : "+v"(lo), "+v"(hi));
    // after: lo = [lo_lo, hi_lo]  (k-slots j=0..1 per half)
    //        hi = [lo_hi, hi_hi]  (k-slots j=4..5 per half)
}

// D[o][r] = sum_k W[o][k] * H[k][r] ; A=W rows o=lane&31, B cols r=lane&31,
// k-slice = 8*(lane>>5)+j for both (shared mapping -> any k-permutation cancels).
// C/D: col=lane&31, row=(reg&3)+8*(reg>>2)+4*(lane>>5)  [verified mapping]
__global__ __launch_bounds__(256, 2)
void mlp_mfma(const float* __restrict__ x,
              const float* __restrict__ W1, const float* __restrict__ b1,
              const float* __restrict__ Wmid, const float* __restrict__ bmid,
              const float* __restrict__ W30, const float* __restrict__ b30,
              float* __restrict__ out, int nrows)
{
    const int lane  = threadIdx.x & 63;
    const int wv    = threadIdx.x >> 6;
    const int tile  = blockIdx.x * 4 + wv;       // 32 rows per wave-tile
    const int r0    = tile * 32;
    if (r0 >= nrows) return;
    const int colr  = lane & 31;                  // batch row within tile (N dim)
    const int half  = lane >> 5;                  // k-group
    const int row   = r0 + colr;

    // ---------------- fc1: K=784 = 49 steps of 16 ----------------
    f32x16 acc0, acc1;
#pragma unroll
    for (int r = 0; r < 16; ++r) { acc0[r] = 0.f; acc1[r] = 0.f; }

    const int   ow1  = colr < 20 ? colr : 19;     // pad rows read garbage (never used)
    const float* xr  = x  + (size_t)row * 784 + half * 8;
    const float* w1r = W1 + (size_t)ow1 * 784 + half * 8;

#pragma unroll 2
    for (int s = 0; s < 49; ++s) {
        const float4 xa = ldf4(xr + s * 16), xb = ldf4(xr + s * 16 + 4);
        const float4 wa = ldf4(w1r + s * 16), wb = ldf4(w1r + s * 16 + 4);
        Frag B = cvt8(xa, xb);
        Frag A = cvt8(wa, wb);
        if (s & 1) {
            acc1 = MFMA(A.h, B.h, acc1);
            acc1 = MFMA(A.l, B.h, acc1);
            acc1 = MFMA(A.h, B.l, acc1);
        } else {
            acc0 = MFMA(A.h, B.h, acc0);
            acc0 = MFMA(A.l, B.h, acc0);
            acc0 = MFMA(A.h, B.l, acc0);
        }
    }

    // bias + relu -> Hv (pad rows forced to exact 0)
    float Hv[16];
#pragma unroll
    for (int r = 0; r < 16; ++r) {
        const int o = (r & 3) + 8 * (r >> 2) + 4 * half;
        const float bv = b1[o < 20 ? o : 0];
        const float v  = fmaxf(acc0[r] + acc1[r] + bv, 0.f);
        Hv[r] = (o < 20) ? v : 0.f;
    }

    // ---------------- fc2..fc29 + fc30: K=20 (step0 k0..15, step1 k16..19) ----
    const int owm = colr < 20 ? colr : 19;
    const int ow3 = colr < 10 ? colr : 9;

#pragma unroll 1
    for (int l = 0; l < 29; ++l) {
        const bool last = (l == 28);
        const float* wrow = last ? (W30 + (size_t)ow3 * 20)
                                 : (Wmid + (size_t)l * 400 + (size_t)owm * 20);
        const float* bl   = last ? b30 : (bmid + l * 20);
        const int    omax = last ? 10 : 20;

        // ---- A fragments (weights, on-the-fly split) ----
        const float4 wa = ldf4(wrow + half * 8), wb = ldf4(wrow + half * 8 + 4);
        Frag A0 = cvt8(wa, wb);
        float4 wc = make_float4(0.f, 0.f, 0.f, 0.f);
        if (!half) wc = ldf4(wrow + 16);          // k=16..19 (h=1 k-range is all pad)
        const short8 A1h = mk8(half ? 0u : packhi2(wc.x, wc.y),
                               half ? 0u : packhi2(wc.z, wc.w), 0u, 0u);
        const short8 A1l = mk8(half ? 0u : packhi2(lopart(wc.x), lopart(wc.y)),
                               half ? 0u : packhi2(lopart(wc.z), lopart(wc.w)), 0u, 0u);

        // ---- B step0 fragments from Hv via permlane32_swap ----
        // local regs 0..3 = rows {0..3 | 4..7}, regs 4..7 = rows {8..11 | 12..15}
        // want word0/1: k=8h+{0..3} -> [plo_lo, phi_lo]; word2/3: k=8h+{4..7} -> [plo_hi, phi_hi]
        unsigned plo0 = packhi2(Hv[0], Hv[1]);
        unsigned plo1 = packhi2(Hv[2], Hv[3]);
        unsigned phi0 = packhi2(Hv[4], Hv[5]);
        unsigned phi1 = packhi2(Hv[6], Hv[7]);
        plswap(plo0, phi0);
        plswap(plo1, phi1);
        const short8 B0h = mk8(plo0, plo1, phi0, phi1);

        unsigned qlo0 = packhi2(lopart(Hv[0]), lopart(Hv[1]));
        unsigned qlo1 = packhi2(lopart(Hv[2]), lopart(Hv[3]));
        unsigned qhi0 = packhi2(lopart(Hv[4]), lopart(Hv[5]));
        unsigned qhi1 = packhi2(lopart(Hv[6]), lopart(Hv[7]));
        plswap(qlo0, qhi0);
        plswap(qlo1, qhi1);
        const short8 B0l = mk8(qlo0, qlo1, qhi0, qhi1);

        // ---- B step1: k=16..19 real only for h=0 (rows 16..19 = regs 8..11, lo half)
        const short8 B1h = mk8(half ? 0u : packhi2(Hv[8], Hv[9]),
                               half ? 0u : packhi2(Hv[10], Hv[11]), 0u, 0u);
        const short8 B1l = mk8(half ? 0u : packhi2(lopart(Hv[8]), lopart(Hv[9])),
                               half ? 0u : packhi2(lopart(Hv[10]), lopart(Hv[11])), 0u, 0u);

        // ---- accumulate: init with bias ----
        f32x16 acc;
#pragma unroll
        for (int r = 0; r < 16; ++r) {
            const int o = (r & 3) + 8 * (r >> 2) + 4 * half;
            const float bv = bl[o < omax ? o : 0];
            acc[r] = (o < omax) ? bv : 0.f;
        }
        acc = MFMA(A0.h, B0h, acc);
        acc = MFMA(A0.l, B0h, acc);
        acc = MFMA(A0.h, B0l, acc);
        acc = MFMA(A1h, B1h, acc);
        acc = MFMA(A1l, B1h, acc);
        acc = MFMA(A1h, B1l, acc);

        if (!last) {
#pragma unroll
            for (int r = 0; r < 16; ++r) {
                const int o = (r & 3) + 8 * (r >> 2) + 4 * half;
                Hv[r] = (o < 20) ? fmaxf(acc[r], 0.f) : 0.f;
            }
        } else {
            // ---- store: o<10 regs -> out[row][o] ----
#pragma unroll
            for (int r = 0; r < 16; ++r) {
                const int o = (r & 3) + 8 * (r >> 2) + 4 * half;
                if (o < 10) out[(size_t)row * 10 + o] = acc[r];
            }
        }
    }
}

extern "C" void kernel_launch(void* const* d_in, const int* in_sizes, int n_in,
                              void* d_out, int out_size, void* d_ws, size_t ws_size,
                              hipStream_t stream)
{
    const float* x    = (const float*)d_in[0];
    const float* W1   = (const float*)d_in[1];
    const float* b1   = (const float*)d_in[2];
    const float* Wmid = (const float*)d_in[3];
    const float* bmid = (const float*)d_in[4];
    const float* W30  = (const float*)d_in[5];
    const float* b30  = (const float*)d_in[6];
    float* out = (float*)d_out;

    const int nrows = in_sizes[0] / 784;
    const int tiles = (nrows + 31) / 32;          // 2048
    const int grid  = (tiles + 3) / 4;            // 512 blocks x 4 waves
    mlp_mfma<<<grid, 256, 0, stream>>>(x, W1, b1, Wmid, bmid, W30, b30, out, nrows);
}